// Round 7
// baseline (1941.508 us; speedup 1.0000x reference)
//
#include <hip/hip_runtime.h>
#include <hip/hip_bf16.h>

// MLA attention. Inputs fp32, internal bf16 MFMA, output fp32. Pipeline:
//   1. convert x -> bf16 [M,K]; convert+transpose weights -> bf16 [N][K]
//      (Wq scaled by log2(e)/sqrt(dh): softmax runs in exp2 domain)
//   2. lat = x @ W_kv                  ([M,32])
//   3. K   = lat @ W_k   -> [M,1024]   (head h = cols h*64..h*64+63)
//   4. V   = lat @ W_v   -> [B,H,dh,T] (transposed: PV A-frags contiguous)
//   5. Q   = x @ W_q     -> [M,1024]
//   6. flash attention, transposed algebra: S^T = K Q^T (row=key, col=query)
//      per-lane-scalar softmax; O^T = V^T P^T. Overwrites own Q tile.
//      One 16-query tile per wave, longest-first dispatch, 8 blocks/CU.
//   7. out = AO @ W_o    -> d_out (fp32)

#define T_SEQ  4096
#define NHEAD  16
#define DHEAD  64
#define DMODEL 1024
#define LATENT 32
#define BATCH  2
#define M_ROWS (BATCH * T_SEQ)

typedef __attribute__((ext_vector_type(8))) short bf16x8;
typedef __attribute__((ext_vector_type(4))) float f32x4;

__device__ __forceinline__ short f2bf(float f) {
  __hip_bfloat16 h = __float2bfloat16(f);
  return __builtin_bit_cast(short, h);
}

// hardware v_exp_f32: computes 2^x  (NOT e^x) — cdna4_isa.md §3
__device__ __forceinline__ float exp2_hw(float x) {
  return __builtin_amdgcn_exp2f(x);
}

// ------------------------------------------------------------- ingress conv
__global__ __launch_bounds__(256)
void convert_in(const float* __restrict__ src, short* __restrict__ dst, int n) {
  int i = (blockIdx.x * 256 + threadIdx.x) * 4;
  if (i >= n) return;
  const f32x4 v = *(const f32x4*)(src + i);
  short4 o;
  o.x = f2bf(v[0]); o.y = f2bf(v[1]); o.z = f2bf(v[2]); o.w = f2bf(v[3]);
  *(short4*)(dst + i) = o;
}

// convert + transpose (+scale): src [K,N] fp32 -> dst [N,K] bf16
__global__ __launch_bounds__(256)
void convert_transpose(const float* __restrict__ src, short* __restrict__ dst,
                       int K, int N, float scale) {
  int idx = blockIdx.x * 256 + threadIdx.x;
  if (idx >= K * N) return;
  int k = idx / N;
  int n = idx - k * N;
  dst[n * K + k] = f2bf(src[idx] * scale);
}

// ---------------------------------------------------------------- GEMM
// C[M,N] = A[M,K] @ B[K,N], Bt = B^T ([N][K] row-major, bf16).
// One wave computes a 16(M) x 64(N) tile; 4 waves/block.
// out_mode 0: bf16 row-major [M,N]
// out_mode 2: bf16 [B,H,dh,T] (V^T; requires N==DMODEL)
// out_mode 3: fp32 row-major [M,N]
__global__ __launch_bounds__(256)
void gemm_bt_kernel(const short* __restrict__ A, const short* __restrict__ Bt,
                    short* __restrict__ Cs, float* __restrict__ Cf,
                    int M, int K, int N, int out_mode) {
  const int tid  = threadIdx.x;
  const int wv   = tid >> 6;
  const int lane = tid & 63;
  const int quad = lane >> 4;
  const int l16  = lane & 15;

  const int Nw = (N + 63) >> 6;
  const int gw = blockIdx.x * 4 + wv;
  const int mt = gw / Nw;
  const int nt = gw - mt * Nw;
  const int m0 = mt * 16;
  const int n0 = nt * 64;
  if (m0 >= M) return;

  f32x4 acc[4] = {};
  const short* Ap = A + (size_t)(m0 + l16) * K + quad * 8;

  for (int k0 = 0; k0 < K; k0 += 32) {
    bf16x8 a = *(const bf16x8*)(Ap + k0);
#pragma unroll
    for (int f = 0; f < 4; ++f) {
      const int n = n0 + f * 16 + l16;
      if (n < N) {   // wave-uniform per f (N multiple of 16)
        bf16x8 b = *(const bf16x8*)(Bt + (size_t)n * K + k0 + quad * 8);
        acc[f] = __builtin_amdgcn_mfma_f32_16x16x32_bf16(a, b, acc[f], 0, 0, 0);
      }
    }
  }

#pragma unroll
  for (int f = 0; f < 4; ++f) {
    const int n = n0 + f * 16 + l16;
    if (n >= N) continue;
#pragma unroll
    for (int r = 0; r < 4; ++r) {
      const int m = m0 + quad * 4 + r;     // C/D layout: row=quad*4+r, col=l16
      if (out_mode == 2) {                 // V^T scatter
        const int b  = m >> 12;            // T_SEQ = 4096
        const int t  = m & (T_SEQ - 1);
        const int h  = n >> 6;             // DHEAD = 64
        const int dh = n & 63;
        Cs[((size_t)(b * NHEAD + h) * DHEAD + dh) * T_SEQ + t] = f2bf(acc[f][r]);
      } else if (out_mode == 3) {
        Cf[(size_t)m * N + n] = acc[f][r];
      } else {
        Cs[(size_t)m * N + n] = f2bf(acc[f][r]);
      }
    }
  }
}

// ---------------------------------------------------------------- attention
// Transposed flash attention, one 16-query tile per wave, 64-key steps.
//   S^T = K Q^T : A-frag = K rows (m=key), B-frag = Q^T (n=query=l16)
//   -> C-layout row=key(quad*4+r), col=query(l16): per-lane-scalar softmax,
//      reduction = 15 in-reg ops + xor16 + xor32. exp2-domain (Wq pre-scaled).
//   P^T -> LDS (short4 writes), read back as B-frags; O^T = V^T P^T.
// 8192 waves / 2048 blocks; longest tiles dispatched first; 8 blocks/CU.
__global__ __launch_bounds__(256, 8)
void attn_kernel(short* __restrict__ Qb, const short* __restrict__ Kb,
                 const short* __restrict__ Vt) {
  __shared__ short Plds[4][2][16 * 72];   // [wave][dbuf][query][64 keys + pad]

  const int tid  = threadIdx.x;
  const int wv   = tid >> 6;
  const int lane = tid & 63;
  const int quad = lane >> 4;
  const int l16  = lane & 15;

  const int gw = blockIdx.x * 4 + wv;     // 0..8191
  const int bh = gw >> 8;                 // 32 (b,h) pairs, 256 tiles each
  const int qt = 255 - (gw & 255);        // longest-first within each bh
  const int b  = bh >> 4;
  const int h  = bh & 15;

  short*       Qp  = Qb + (size_t)b * T_SEQ * DMODEL + h * DHEAD;
  const short* Kp  = Kb + (size_t)b * T_SEQ * DMODEL + h * DHEAD;
  const short* Vbh = Vt + ((size_t)bh) * DHEAD * T_SEQ;   // [dh][T]

  const int q0   = qt * 16;
  const int qmax = q0 + 15;
  const int q    = q0 + l16;              // this lane's query (column)

  // Q^T B-fragments: n = l16 (query), k = dh chunk
  const bf16x8 qf0 = *(const bf16x8*)(Qp + (size_t)(q0 + l16) * DMODEL + quad * 8);
  const bf16x8 qf1 = *(const bf16x8*)(Qp + (size_t)(q0 + l16) * DMODEL + 32 + quad * 8);

  f32x4 o[4] = {};
  float m = -1e30f, l = 0.0f;
  int pb = 0;

#pragma unroll 1
  for (int k0 = 0; k0 <= qmax; k0 += 64) {
    // ---- S^T = K Q^T for 64 keys x 16 queries (4 key tiles)
    f32x4 st[4] = {};
#pragma unroll
    for (int mt = 0; mt < 4; ++mt) {
      const short* kr = Kp + (size_t)(k0 + mt * 16 + l16) * DMODEL + quad * 8;
      const bf16x8 kf0 = *(const bf16x8*)(kr);
      const bf16x8 kf1 = *(const bf16x8*)(kr + 32);
      st[mt] = __builtin_amdgcn_mfma_f32_16x16x32_bf16(kf0, qf0, st[mt], 0, 0, 0);
      st[mt] = __builtin_amdgcn_mfma_f32_16x16x32_bf16(kf1, qf1, st[mt], 0, 0, 0);
    }

    // ---- V^T A-fragments: independent of softmax — issue loads early so
    // vmcnt latency overlaps the exp chain below.
    bf16x8 vf0[4], vf1[4];
#pragma unroll
    for (int f = 0; f < 4; ++f) {
      const short* vr = Vbh + (size_t)(f * 16 + l16) * T_SEQ + k0 + quad * 8;
      vf0[f] = *(const bf16x8*)(vr);
      vf1[f] = *(const bf16x8*)(vr + 32);
    }

    // ---- per-lane softmax over 16 key-scores of query l16 (exp2 domain)
    float sc[4][4];
    float vmax = -1e30f;
#pragma unroll
    for (int mt = 0; mt < 4; ++mt)
#pragma unroll
      for (int r = 0; r < 4; ++r) {
        const int key = k0 + mt * 16 + quad * 4 + r;
        const float v = (key <= q) ? st[mt][r] : -1e9f;   // pre-scaled by log2e/8
        sc[mt][r] = v;
        vmax = fmaxf(vmax, v);
      }
    vmax = fmaxf(vmax, __shfl_xor(vmax, 16));
    vmax = fmaxf(vmax, __shfl_xor(vmax, 32));
    const float mnew  = fmaxf(m, vmax);
    const float alpha = exp2_hw(m - mnew);
    m = mnew;
    float s = 0.0f;
#pragma unroll
    for (int mt = 0; mt < 4; ++mt)
#pragma unroll
      for (int r = 0; r < 4; ++r) {
        sc[mt][r] = exp2_hw(sc[mt][r] - mnew);
        s += sc[mt][r];
      }
    s += __shfl_xor(s, 16);
    s += __shfl_xor(s, 32);
    l = l * alpha + s;
#pragma unroll
    for (int f = 0; f < 4; ++f)
#pragma unroll
      for (int r = 0; r < 4; ++r) o[f][r] *= alpha;

    // ---- P (row=query l16, cols=keys) -> LDS; read back as B-frags.
    // Per-wave double buffer + explicit lgkmcnt(0) drain.
    short* P = &Plds[wv][pb][0];
    pb ^= 1;
    asm volatile("" ::: "memory");
#pragma unroll
    for (int mt = 0; mt < 4; ++mt) {
      short4 w;
      w.x = f2bf(sc[mt][0]); w.y = f2bf(sc[mt][1]);
      w.z = f2bf(sc[mt][2]); w.w = f2bf(sc[mt][3]);
      *(short4*)(P + l16 * 72 + mt * 16 + quad * 4) = w;
    }
    asm volatile("" ::: "memory");
    __builtin_amdgcn_s_waitcnt(0xC07F);   // lgkmcnt(0)
    asm volatile("" ::: "memory");
    const bf16x8 pf0 = *(const bf16x8*)(P + l16 * 72 + quad * 8);
    const bf16x8 pf1 = *(const bf16x8*)(P + l16 * 72 + 32 + quad * 8);
    asm volatile("" ::: "memory");

    // ---- O^T += V^T P^T
#pragma unroll
    for (int f = 0; f < 4; ++f) {
      o[f] = __builtin_amdgcn_mfma_f32_16x16x32_bf16(vf0[f], pf0, o[f], 0, 0, 0);
      o[f] = __builtin_amdgcn_mfma_f32_16x16x32_bf16(vf1[f], pf1, o[f], 0, 0, 0);
    }
  }

  // ---- epilogue: O^T C-layout row = dh = f*16+quad*4+r, col = query l16.
  const float inv = 1.0f / l;
#pragma unroll
  for (int f = 0; f < 4; ++f) {
    short4 w;
    w.x = f2bf(o[f][0] * inv);
    w.y = f2bf(o[f][1] * inv);
    w.z = f2bf(o[f][2] * inv);
    w.w = f2bf(o[f][3] * inv);
    *(short4*)(Qp + (size_t)(q0 + l16) * DMODEL + f * 16 + quad * 4) = w;
  }
}

// ---------------------------------------------------------------- launch
extern "C" void kernel_launch(void* const* d_in, const int* in_sizes, int n_in,
                              void* d_out, int out_size, void* d_ws, size_t ws_size,
                              hipStream_t stream) {
  const float* x   = (const float*)d_in[0];   // [2,4096,1024]
  const float* Wkv = (const float*)d_in[1];   // [1024,32]
  const float* Wk  = (const float*)d_in[2];   // [32,1024]
  const float* Wv  = (const float*)d_in[3];   // [32,1024]
  const float* Wq  = (const float*)d_in[4];   // [1024,1024]
  const float* Wo  = (const float*)d_in[5];   // [1024,1024]

  char* p = (char*)d_ws;
  auto carve = [&](size_t n) {
    char* r = p;
    p += (n + 255) & ~(size_t)255;
    return r;
  };
  short* xbf  = (short*)carve((size_t)M_ROWS * DMODEL * 2);   // 16 MB
  short* Qb   = (short*)carve((size_t)M_ROWS * DMODEL * 2);   // 16 MB (Q -> AO)
  short* Kb   = (short*)carve((size_t)M_ROWS * DMODEL * 2);   // 16 MB
  short* Vtb  = (short*)carve((size_t)M_ROWS * DMODEL * 2);   // 16 MB
  short* lat  = (short*)carve((size_t)M_ROWS * LATENT * 2);   // 512 KB
  short* WqT  = (short*)carve((size_t)DMODEL * DMODEL * 2);   // 2 MB
  short* WoT  = (short*)carve((size_t)DMODEL * DMODEL * 2);   // 2 MB
  short* WkvT = (short*)carve((size_t)DMODEL * LATENT * 2);   // 64 KB
  short* WkT  = (short*)carve((size_t)LATENT * DMODEL * 2);   // 64 KB
  short* WvT  = (short*)carve((size_t)LATENT * DMODEL * 2);   // 64 KB

  convert_in<<<(M_ROWS * DMODEL / 4 + 255) / 256, 256, 0, stream>>>(x, xbf, M_ROWS * DMODEL);
  convert_transpose<<<(DMODEL * LATENT + 255) / 256, 256, 0, stream>>>(Wkv, WkvT, DMODEL, LATENT, 1.0f);
  convert_transpose<<<(LATENT * DMODEL + 255) / 256, 256, 0, stream>>>(Wk, WkT, LATENT, DMODEL, 1.0f);
  convert_transpose<<<(LATENT * DMODEL + 255) / 256, 256, 0, stream>>>(Wv, WvT, LATENT, DMODEL, 1.0f);
  // Wq scale = (1/sqrt(64)) * log2(e): softmax computed with exp2
  convert_transpose<<<(DMODEL * DMODEL + 255) / 256, 256, 0, stream>>>(Wq, WqT, DMODEL, DMODEL, 0.1803368801111f);
  convert_transpose<<<(DMODEL * DMODEL + 255) / 256, 256, 0, stream>>>(Wo, WoT, DMODEL, DMODEL, 1.0f);

  auto gemm = [&](const short* A, const short* Bt, short* Cs, float* Cf,
                  int M, int K, int N, int mode) {
    int Nw = (N + 63) >> 6;
    int waves = (M / 16) * Nw;
    int blocks = (waves + 3) / 4;
    gemm_bt_kernel<<<blocks, 256, 0, stream>>>(A, Bt, Cs, Cf, M, K, N, mode);
  };

  gemm(xbf, WkvT, lat, nullptr, M_ROWS, DMODEL, LATENT, 0);   // lat = x @ W_kv
  gemm(lat, WkT,  Kb,  nullptr, M_ROWS, LATENT, DMODEL, 0);   // K  [M,1024]
  gemm(lat, WvT,  Vtb, nullptr, M_ROWS, LATENT, DMODEL, 2);   // V^T [B,H,dh,T]
  gemm(xbf, WqT,  Qb,  nullptr, M_ROWS, DMODEL, DMODEL, 0);   // Q (pre-scaled)

  attn_kernel<<<2048, 256, 0, stream>>>(Qb, Kb, Vtb);

  gemm(Qb, WoT, nullptr, (float*)d_out, M_ROWS, DMODEL, DMODEL, 3);  // out fp32
}

// Round 8
// 1220.472 us; speedup vs baseline: 1.5908x; 1.5908x over previous
//
#include <hip/hip_runtime.h>
#include <hip/hip_bf16.h>

// MLA attention. Inputs fp32, internal bf16 MFMA, output fp32. Pipeline:
//   1. convert x -> bf16 [M,K]; convert+transpose weights -> bf16 [N][K]
//      (Wq scaled by log2(e)/sqrt(dh): softmax runs in exp2 domain)
//   2. lat = x @ W_kv                  ([M,32])
//   3. K   = lat @ W_k   -> [M,1024]   (head h = cols h*64..h*64+63)
//   4. V   = lat @ W_v   -> [B,H,dh,T] (transposed: PV A-frags contiguous)
//   5. Q   = x @ W_q     -> [M,1024]
//   6. flash attention, transposed algebra: S^T = K Q^T (row=key, col=query)
//      per-lane-scalar softmax; O^T = V^T P^T. K prefetched one iteration
//      ahead; V issued before softmax. Overwrites own Q tile.
//   7. out = AO @ W_o    -> d_out (fp32)

#define T_SEQ  4096
#define NHEAD  16
#define DHEAD  64
#define DMODEL 1024
#define LATENT 32
#define BATCH  2
#define M_ROWS (BATCH * T_SEQ)

typedef __attribute__((ext_vector_type(8))) short bf16x8;
typedef __attribute__((ext_vector_type(4))) float f32x4;

__device__ __forceinline__ short f2bf(float f) {
  __hip_bfloat16 h = __float2bfloat16(f);
  return __builtin_bit_cast(short, h);
}

// hardware v_exp_f32: computes 2^x (NOT e^x) — cdna4_isa.md §3
__device__ __forceinline__ float exp2_hw(float x) {
  return __builtin_amdgcn_exp2f(x);
}

// ------------------------------------------------------------- ingress conv
__global__ __launch_bounds__(256)
void convert_in(const float* __restrict__ src, short* __restrict__ dst, int n) {
  int i = (blockIdx.x * 256 + threadIdx.x) * 4;
  if (i >= n) return;
  const f32x4 v = *(const f32x4*)(src + i);
  short4 o;
  o.x = f2bf(v[0]); o.y = f2bf(v[1]); o.z = f2bf(v[2]); o.w = f2bf(v[3]);
  *(short4*)(dst + i) = o;
}

// convert + transpose (+scale): src [K,N] fp32 -> dst [N,K] bf16
__global__ __launch_bounds__(256)
void convert_transpose(const float* __restrict__ src, short* __restrict__ dst,
                       int K, int N, float scale) {
  int idx = blockIdx.x * 256 + threadIdx.x;
  if (idx >= K * N) return;
  int k = idx / N;
  int n = idx - k * N;
  dst[n * K + k] = f2bf(src[idx] * scale);
}

// ---------------------------------------------------------------- GEMM
// C[M,N] = A[M,K] @ B[K,N], Bt = B^T ([N][K] row-major, bf16).
// One wave computes a 16(M) x 64(N) tile; 4 waves/block.
// out_mode 0: bf16 row-major [M,N]
// out_mode 2: bf16 [B,H,dh,T] (V^T; requires N==DMODEL)
// out_mode 3: fp32 row-major [M,N]
__global__ __launch_bounds__(256)
void gemm_bt_kernel(const short* __restrict__ A, const short* __restrict__ Bt,
                    short* __restrict__ Cs, float* __restrict__ Cf,
                    int M, int K, int N, int out_mode) {
  const int tid  = threadIdx.x;
  const int wv   = tid >> 6;
  const int lane = tid & 63;
  const int quad = lane >> 4;
  const int l16  = lane & 15;

  const int Nw = (N + 63) >> 6;
  const int gw = blockIdx.x * 4 + wv;
  const int mt = gw / Nw;
  const int nt = gw - mt * Nw;
  const int m0 = mt * 16;
  const int n0 = nt * 64;
  if (m0 >= M) return;

  f32x4 acc[4] = {};
  const short* Ap = A + (size_t)(m0 + l16) * K + quad * 8;

  for (int k0 = 0; k0 < K; k0 += 32) {
    bf16x8 a = *(const bf16x8*)(Ap + k0);
#pragma unroll
    for (int f = 0; f < 4; ++f) {
      const int n = n0 + f * 16 + l16;
      if (n < N) {   // wave-uniform per f (N multiple of 16)
        bf16x8 b = *(const bf16x8*)(Bt + (size_t)n * K + k0 + quad * 8);
        acc[f] = __builtin_amdgcn_mfma_f32_16x16x32_bf16(a, b, acc[f], 0, 0, 0);
      }
    }
  }

#pragma unroll
  for (int f = 0; f < 4; ++f) {
    const int n = n0 + f * 16 + l16;
    if (n >= N) continue;
#pragma unroll
    for (int r = 0; r < 4; ++r) {
      const int m = m0 + quad * 4 + r;     // C/D layout: row=quad*4+r, col=l16
      if (out_mode == 2) {                 // V^T scatter
        const int b  = m >> 12;            // T_SEQ = 4096
        const int t  = m & (T_SEQ - 1);
        const int h  = n >> 6;             // DHEAD = 64
        const int dh = n & 63;
        Cs[((size_t)(b * NHEAD + h) * DHEAD + dh) * T_SEQ + t] = f2bf(acc[f][r]);
      } else if (out_mode == 3) {
        Cf[(size_t)m * N + n] = acc[f][r];
      } else {
        Cs[(size_t)m * N + n] = f2bf(acc[f][r]);
      }
    }
  }
}

// ---------------------------------------------------------------- attention
// Transposed flash attention, one 16-query tile per wave, 64-key steps,
// K software-pipelined one iteration ahead, V issued ahead of softmax.
//   S^T = K Q^T : A-frag = K rows (m=key), B-frag = Q^T (n=query=l16)
//   -> C-layout row=key(quad*4+r), col=query(l16): per-lane-scalar softmax,
//      reduction = 15 in-reg ops + xor16 + xor32, exp2-domain.
//   P^T -> LDS (short4 writes), read back as B-frags; O^T = V^T P^T.
// 8192 waves / 2048 blocks; longest tiles first; 4 blocks/CU (128-VGPR cap).
__global__ __launch_bounds__(256, 4)
void attn_kernel(short* __restrict__ Qb, const short* __restrict__ Kb,
                 const short* __restrict__ Vt) {
  __shared__ short Plds[4][2][16 * 72];   // [wave][dbuf][query][64 keys + pad]

  const int tid  = threadIdx.x;
  const int wv   = tid >> 6;
  const int lane = tid & 63;
  const int quad = lane >> 4;
  const int l16  = lane & 15;

  const int gw = blockIdx.x * 4 + wv;     // 0..8191
  const int bh = gw >> 8;                 // 32 (b,h) pairs, 256 tiles each
  const int qt = 255 - (gw & 255);        // longest-first within each bh
  const int b  = bh >> 4;
  const int h  = bh & 15;

  short*       Qp  = Qb + (size_t)b * T_SEQ * DMODEL + h * DHEAD;
  const short* Kp  = Kb + (size_t)b * T_SEQ * DMODEL + h * DHEAD;
  const short* Vbh = Vt + ((size_t)bh) * DHEAD * T_SEQ;   // [dh][T]

  const int q0   = qt * 16;
  const int qmax = q0 + 15;
  const int q    = q0 + l16;              // this lane's query (column)

  // Q^T B-fragments: n = l16 (query), k = dh chunk
  const bf16x8 qf0 = *(const bf16x8*)(Qp + (size_t)(q0 + l16) * DMODEL + quad * 8);
  const bf16x8 qf1 = *(const bf16x8*)(Qp + (size_t)(q0 + l16) * DMODEL + 32 + quad * 8);

  f32x4 o[4] = {};
  float m = -1e30f, l = 0.0f;
  int pb = 0;

  // ---- K prefetch for k0 = 0 (A-frags: 4 key tiles x 2 dh chunks)
  bf16x8 kf0[4], kf1[4];
#pragma unroll
  for (int mt = 0; mt < 4; ++mt) {
    const short* kr = Kp + (size_t)(mt * 16 + l16) * DMODEL + quad * 8;
    kf0[mt] = *(const bf16x8*)(kr);
    kf1[mt] = *(const bf16x8*)(kr + 32);
  }

#pragma unroll 1
  for (int k0 = 0; k0 <= qmax; k0 += 64) {
    // ---- issue V loads now; consumed only at the PV tail (latency overlaps
    // S-MFMAs + softmax).
    bf16x8 vf0[4], vf1[4];
#pragma unroll
    for (int f = 0; f < 4; ++f) {
      const short* vr = Vbh + (size_t)(f * 16 + l16) * T_SEQ + k0 + quad * 8;
      vf0[f] = *(const bf16x8*)(vr);
      vf1[f] = *(const bf16x8*)(vr + 32);
    }

    // ---- S^T = K Q^T (uses K prefetched last iteration)
    f32x4 st[4] = {};
#pragma unroll
    for (int mt = 0; mt < 4; ++mt) {
      st[mt] = __builtin_amdgcn_mfma_f32_16x16x32_bf16(kf0[mt], qf0, st[mt], 0, 0, 0);
      st[mt] = __builtin_amdgcn_mfma_f32_16x16x32_bf16(kf1[mt], qf1, st[mt], 0, 0, 0);
    }

    // ---- prefetch K for next iteration (wave-uniform branch)
    const int kn = k0 + 64;
    if (kn <= qmax) {
#pragma unroll
      for (int mt = 0; mt < 4; ++mt) {
        const short* kr = Kp + (size_t)(kn + mt * 16 + l16) * DMODEL + quad * 8;
        kf0[mt] = *(const bf16x8*)(kr);
        kf1[mt] = *(const bf16x8*)(kr + 32);
      }
    }

    // ---- per-lane softmax over 16 key-scores of query l16 (exp2 domain)
    float sc[4][4];
    float vmax = -1e30f;
#pragma unroll
    for (int mt = 0; mt < 4; ++mt)
#pragma unroll
      for (int r = 0; r < 4; ++r) {
        const int key = k0 + mt * 16 + quad * 4 + r;
        const float v = (key <= q) ? st[mt][r] : -1e9f;   // pre-scaled log2e/8
        sc[mt][r] = v;
        vmax = fmaxf(vmax, v);
      }
    vmax = fmaxf(vmax, __shfl_xor(vmax, 16));
    vmax = fmaxf(vmax, __shfl_xor(vmax, 32));
    const float mnew  = fmaxf(m, vmax);
    const float alpha = exp2_hw(m - mnew);
    m = mnew;
    float s = 0.0f;
#pragma unroll
    for (int mt = 0; mt < 4; ++mt)
#pragma unroll
      for (int r = 0; r < 4; ++r) {
        sc[mt][r] = exp2_hw(sc[mt][r] - mnew);
        s += sc[mt][r];
      }
    s += __shfl_xor(s, 16);
    s += __shfl_xor(s, 32);
    l = l * alpha + s;
#pragma unroll
    for (int f = 0; f < 4; ++f)
#pragma unroll
      for (int r = 0; r < 4; ++r) o[f][r] *= alpha;

    // ---- P (row=query l16, cols=keys) -> LDS; read back as B-frags.
    // Per-wave double buffer + explicit lgkmcnt(0) drain.
    short* P = &Plds[wv][pb][0];
    pb ^= 1;
    asm volatile("" ::: "memory");
#pragma unroll
    for (int mt = 0; mt < 4; ++mt) {
      short4 w;
      w.x = f2bf(sc[mt][0]); w.y = f2bf(sc[mt][1]);
      w.z = f2bf(sc[mt][2]); w.w = f2bf(sc[mt][3]);
      *(short4*)(P + l16 * 72 + mt * 16 + quad * 4) = w;
    }
    asm volatile("" ::: "memory");
    __builtin_amdgcn_s_waitcnt(0xC07F);   // lgkmcnt(0)
    asm volatile("" ::: "memory");
    const bf16x8 pf0 = *(const bf16x8*)(P + l16 * 72 + quad * 8);
    const bf16x8 pf1 = *(const bf16x8*)(P + l16 * 72 + 32 + quad * 8);
    asm volatile("" ::: "memory");

    // ---- O^T += V^T P^T
#pragma unroll
    for (int f = 0; f < 4; ++f) {
      o[f] = __builtin_amdgcn_mfma_f32_16x16x32_bf16(vf0[f], pf0, o[f], 0, 0, 0);
      o[f] = __builtin_amdgcn_mfma_f32_16x16x32_bf16(vf1[f], pf1, o[f], 0, 0, 0);
    }
  }

  // ---- epilogue: O^T C-layout row = dh = f*16+quad*4+r, col = query l16.
  const float inv = 1.0f / l;
#pragma unroll
  for (int f = 0; f < 4; ++f) {
    short4 w;
    w.x = f2bf(o[f][0] * inv);
    w.y = f2bf(o[f][1] * inv);
    w.z = f2bf(o[f][2] * inv);
    w.w = f2bf(o[f][3] * inv);
    *(short4*)(Qp + (size_t)(q0 + l16) * DMODEL + f * 16 + quad * 4) = w;
  }
}

// ---------------------------------------------------------------- launch
extern "C" void kernel_launch(void* const* d_in, const int* in_sizes, int n_in,
                              void* d_out, int out_size, void* d_ws, size_t ws_size,
                              hipStream_t stream) {
  const float* x   = (const float*)d_in[0];   // [2,4096,1024]
  const float* Wkv = (const float*)d_in[1];   // [1024,32]
  const float* Wk  = (const float*)d_in[2];   // [32,1024]
  const float* Wv  = (const float*)d_in[3];   // [32,1024]
  const float* Wq  = (const float*)d_in[4];   // [1024,1024]
  const float* Wo  = (const float*)d_in[5];   // [1024,1024]

  char* p = (char*)d_ws;
  auto carve = [&](size_t n) {
    char* r = p;
    p += (n + 255) & ~(size_t)255;
    return r;
  };
  short* xbf  = (short*)carve((size_t)M_ROWS * DMODEL * 2);   // 16 MB
  short* Qb   = (short*)carve((size_t)M_ROWS * DMODEL * 2);   // 16 MB (Q -> AO)
  short* Kb   = (short*)carve((size_t)M_ROWS * DMODEL * 2);   // 16 MB
  short* Vtb  = (short*)carve((size_t)M_ROWS * DMODEL * 2);   // 16 MB
  short* lat  = (short*)carve((size_t)M_ROWS * LATENT * 2);   // 512 KB
  short* WqT  = (short*)carve((size_t)DMODEL * DMODEL * 2);   // 2 MB
  short* WoT  = (short*)carve((size_t)DMODEL * DMODEL * 2);   // 2 MB
  short* WkvT = (short*)carve((size_t)DMODEL * LATENT * 2);   // 64 KB
  short* WkT  = (short*)carve((size_t)LATENT * DMODEL * 2);   // 64 KB
  short* WvT  = (short*)carve((size_t)LATENT * DMODEL * 2);   // 64 KB

  convert_in<<<(M_ROWS * DMODEL / 4 + 255) / 256, 256, 0, stream>>>(x, xbf, M_ROWS * DMODEL);
  convert_transpose<<<(DMODEL * LATENT + 255) / 256, 256, 0, stream>>>(Wkv, WkvT, DMODEL, LATENT, 1.0f);
  convert_transpose<<<(LATENT * DMODEL + 255) / 256, 256, 0, stream>>>(Wk, WkT, LATENT, DMODEL, 1.0f);
  convert_transpose<<<(LATENT * DMODEL + 255) / 256, 256, 0, stream>>>(Wv, WvT, LATENT, DMODEL, 1.0f);
  // Wq scale = (1/sqrt(64)) * log2(e): softmax computed with exp2
  convert_transpose<<<(DMODEL * DMODEL + 255) / 256, 256, 0, stream>>>(Wq, WqT, DMODEL, DMODEL, 0.1803368801111f);
  convert_transpose<<<(DMODEL * DMODEL + 255) / 256, 256, 0, stream>>>(Wo, WoT, DMODEL, DMODEL, 1.0f);

  auto gemm = [&](const short* A, const short* Bt, short* Cs, float* Cf,
                  int M, int K, int N, int mode) {
    int Nw = (N + 63) >> 6;
    int waves = (M / 16) * Nw;
    int blocks = (waves + 3) / 4;
    gemm_bt_kernel<<<blocks, 256, 0, stream>>>(A, Bt, Cs, Cf, M, K, N, mode);
  };

  gemm(xbf, WkvT, lat, nullptr, M_ROWS, DMODEL, LATENT, 0);   // lat = x @ W_kv
  gemm(lat, WkT,  Kb,  nullptr, M_ROWS, LATENT, DMODEL, 0);   // K  [M,1024]
  gemm(lat, WvT,  Vtb, nullptr, M_ROWS, LATENT, DMODEL, 2);   // V^T [B,H,dh,T]
  gemm(xbf, WqT,  Qb,  nullptr, M_ROWS, DMODEL, DMODEL, 0);   // Q (pre-scaled)

  attn_kernel<<<2048, 256, 0, stream>>>(Qb, Kb, Vtb);

  gemm(Qb, WoT, nullptr, (float*)d_out, M_ROWS, DMODEL, DMODEL, 3);  // out fp32
}

// Round 9
// 569.018 us; speedup vs baseline: 3.4120x; 2.1449x over previous
//
#include <hip/hip_runtime.h>
#include <hip/hip_bf16.h>

// MLA attention. Inputs fp32, internal bf16 MFMA, output fp32. Pipeline:
//   1. convert x -> bf16 [M,K]; convert+transpose weights -> bf16 [N][K]
//      (Wq scaled by log2(e)/sqrt(dh): softmax runs in exp2 domain)
//   2. lat = x @ W_kv                  ([M,32])
//   3. K   = lat @ W_k   -> [M,1024]   (head h = cols h*64..h*64+63)
//   4. V   = lat @ W_v   -> [B,H,dh,T] (transposed: PV A-frags contiguous)
//   5. Q   = x @ W_q     -> [M,1024]
//   6. flash attention: 64-query blocks, K/V staged in LDS via async
//      global_load_lds (shared by 4 waves), transposed algebra
//      S^T = K Q^T, per-lane-scalar softmax, O^T = V^T P^T.
//      XCD-swizzled dispatch (4 bh per XCD -> K/V L2-resident).
//   7. out = AO @ W_o    -> d_out (fp32)

#define T_SEQ  4096
#define NHEAD  16
#define DHEAD  64
#define DMODEL 1024
#define LATENT 32
#define BATCH  2
#define M_ROWS (BATCH * T_SEQ)

typedef __attribute__((ext_vector_type(8))) short bf16x8;
typedef __attribute__((ext_vector_type(4))) float f32x4;

__device__ __forceinline__ short f2bf(float f) {
  __hip_bfloat16 h = __float2bfloat16(f);
  return __builtin_bit_cast(short, h);
}

// hardware v_exp_f32: computes 2^x (NOT e^x) — cdna4_isa.md §3
__device__ __forceinline__ float exp2_hw(float x) {
  return __builtin_amdgcn_exp2f(x);
}

// async global->LDS, 16B per lane. LDS dest = wave-uniform base + lane*16.
__device__ __forceinline__ void gld_lds16(const short* g, short* l) {
  __builtin_amdgcn_global_load_lds(
      (const __attribute__((address_space(1))) void*)g,
      (__attribute__((address_space(3))) void*)l, 16, 0, 0);
}

// ------------------------------------------------------------- ingress conv
__global__ __launch_bounds__(256)
void convert_in(const float* __restrict__ src, short* __restrict__ dst, int n) {
  int i = (blockIdx.x * 256 + threadIdx.x) * 4;
  if (i >= n) return;
  const f32x4 v = *(const f32x4*)(src + i);
  short4 o;
  o.x = f2bf(v[0]); o.y = f2bf(v[1]); o.z = f2bf(v[2]); o.w = f2bf(v[3]);
  *(short4*)(dst + i) = o;
}

// convert + transpose (+scale): src [K,N] fp32 -> dst [N,K] bf16
__global__ __launch_bounds__(256)
void convert_transpose(const float* __restrict__ src, short* __restrict__ dst,
                       int K, int N, float scale) {
  int idx = blockIdx.x * 256 + threadIdx.x;
  if (idx >= K * N) return;
  int k = idx / N;
  int n = idx - k * N;
  dst[n * K + k] = f2bf(src[idx] * scale);
}

// ---------------------------------------------------------------- GEMM
// C[M,N] = A[M,K] @ B[K,N], Bt = B^T ([N][K] row-major, bf16).
// One wave computes a 16(M) x 64(N) tile; 4 waves/block.
// out_mode 0: bf16 row-major [M,N]
// out_mode 2: bf16 [B,H,dh,T] (V^T; requires N==DMODEL)
// out_mode 3: fp32 row-major [M,N]
__global__ __launch_bounds__(256)
void gemm_bt_kernel(const short* __restrict__ A, const short* __restrict__ Bt,
                    short* __restrict__ Cs, float* __restrict__ Cf,
                    int M, int K, int N, int out_mode) {
  const int tid  = threadIdx.x;
  const int wv   = tid >> 6;
  const int lane = tid & 63;
  const int quad = lane >> 4;
  const int l16  = lane & 15;

  const int Nw = (N + 63) >> 6;
  const int gw = blockIdx.x * 4 + wv;
  const int mt = gw / Nw;
  const int nt = gw - mt * Nw;
  const int m0 = mt * 16;
  const int n0 = nt * 64;
  if (m0 >= M) return;

  f32x4 acc[4] = {};
  const short* Ap = A + (size_t)(m0 + l16) * K + quad * 8;

  for (int k0 = 0; k0 < K; k0 += 32) {
    bf16x8 a = *(const bf16x8*)(Ap + k0);
#pragma unroll
    for (int f = 0; f < 4; ++f) {
      const int n = n0 + f * 16 + l16;
      if (n < N) {   // wave-uniform per f (N multiple of 16)
        bf16x8 b = *(const bf16x8*)(Bt + (size_t)n * K + k0 + quad * 8);
        acc[f] = __builtin_amdgcn_mfma_f32_16x16x32_bf16(a, b, acc[f], 0, 0, 0);
      }
    }
  }

#pragma unroll
  for (int f = 0; f < 4; ++f) {
    const int n = n0 + f * 16 + l16;
    if (n >= N) continue;
#pragma unroll
    for (int r = 0; r < 4; ++r) {
      const int m = m0 + quad * 4 + r;     // C/D layout: row=quad*4+r, col=l16
      if (out_mode == 2) {                 // V^T scatter
        const int b  = m >> 12;            // T_SEQ = 4096
        const int t  = m & (T_SEQ - 1);
        const int h  = n >> 6;             // DHEAD = 64
        const int dh = n & 63;
        Cs[((size_t)(b * NHEAD + h) * DHEAD + dh) * T_SEQ + t] = f2bf(acc[f][r]);
      } else if (out_mode == 3) {
        Cf[(size_t)m * N + n] = acc[f][r];
      } else {
        Cs[(size_t)m * N + n] = f2bf(acc[f][r]);
      }
    }
  }
}

// ---------------------------------------------------------------- attention
// Block = 4 waves = 64 queries (wave wv owns queries q0+wv*16 .. +15).
// Per 64-key step: block cooperatively stages K-tile [64k x 64dh] and
// V^T-tile [64dh x 64k] into LDS (global_load_lds w16, XOR-chunk swizzle),
// then each wave: S^T = K Q^T (A-frags from Klds), per-lane softmax (exp2),
// P roundtrip through wave-private LDS, O^T += V^T P^T (A-frags from Vlds).
// Grid 2048: xcd=idx&7, 4 bh per xcd (K/V slices L2-resident), longest-first.
__global__ __launch_bounds__(256, 6)
void attn_kernel(short* __restrict__ Qb, const short* __restrict__ Kb,
                 const short* __restrict__ Vt) {
  __shared__ short Klds[64 * 64];        // [key][dh chunk swizzled]   8 KB
  __shared__ short Vlds[64 * 64];        // [dh][key chunk swizzled]   8 KB
  __shared__ short Plds[4][16 * 72];     // per-wave P^T                9 KB

  const int tid  = threadIdx.x;
  const int wv   = tid >> 6;
  const int lane = tid & 63;
  const int quad = lane >> 4;
  const int l16  = lane & 15;

  const int idx = blockIdx.x;
  const int xcd = idx & 7;
  const int j   = idx >> 3;               // 0..255
  const int bh  = xcd * 4 + (j & 3);      // 4 bh per XCD
  const int qb  = 63 - (j >> 2);          // longest-first
  const int b   = bh >> 4;
  const int h   = bh & 15;

  short*       Qp  = Qb + (size_t)b * T_SEQ * DMODEL + h * DHEAD;
  const short* Kp  = Kb + (size_t)b * T_SEQ * DMODEL + h * DHEAD;
  const short* Vbh = Vt + ((size_t)bh) * DHEAD * T_SEQ;   // [dh][T]

  const int q0       = qb * 64;
  const int qmax_blk = q0 + 63;
  const int qw       = q0 + wv * 16;      // this wave's query base
  const int q        = qw + l16;          // this lane's query (column)

  // staging geometry (per wave, 2 instr per buffer): 8 rows x 128 B each
  const int srow0 = wv * 16 + (lane >> 3);        // i=0 row offset
  const int schk  = (lane & 7) ^ (srow0 & 7);     // XOR chunk swizzle (i=0)
  const int srow1 = srow0 + 8;
  const int schk1 = (lane & 7) ^ (srow1 & 7);

  // Q^T B-fragments
  const bf16x8 qf0 = *(const bf16x8*)(Qp + (size_t)(qw + l16) * DMODEL + quad * 8);
  const bf16x8 qf1 = *(const bf16x8*)(Qp + (size_t)(qw + l16) * DMODEL + 32 + quad * 8);

  f32x4 o[4] = {};
  float m = -1e30f, l = 0.0f;
  short* P = &Plds[wv][0];

#pragma unroll 1
  for (int k0 = 0; k0 <= qmax_blk; k0 += 64) {
    // ---- stage K[k0+0..63][dh 0..63] and V^T[dh 0..63][k0+0..63] -> LDS
    gld_lds16(Kp + (size_t)(k0 + srow0) * DMODEL + schk * 8,  &Klds[(wv * 16) * 64]);
    gld_lds16(Kp + (size_t)(k0 + srow1) * DMODEL + schk1 * 8, &Klds[(wv * 16 + 8) * 64]);
    gld_lds16(Vbh + (size_t)srow0 * T_SEQ + k0 + schk * 8,    &Vlds[(wv * 16) * 64]);
    gld_lds16(Vbh + (size_t)srow1 * T_SEQ + k0 + schk1 * 8,   &Vlds[(wv * 16 + 8) * 64]);
    __builtin_amdgcn_s_waitcnt(0x0F70);   // vmcnt(0)
    __syncthreads();

    // ---- S^T = K Q^T (A-frags from Klds, swizzled chunks)
    f32x4 st[4];
#pragma unroll
    for (int mt = 0; mt < 4; ++mt) {
      const int R = mt * 16 + l16;
      const bf16x8 kf0 = *(const bf16x8*)&Klds[R * 64 + ((quad    ) ^ (R & 7)) * 8];
      const bf16x8 kf1 = *(const bf16x8*)&Klds[R * 64 + ((quad + 4) ^ (R & 7)) * 8];
      f32x4 z = {};
      z = __builtin_amdgcn_mfma_f32_16x16x32_bf16(kf0, qf0, z, 0, 0, 0);
      st[mt] = __builtin_amdgcn_mfma_f32_16x16x32_bf16(kf1, qf1, z, 0, 0, 0);
    }

    // ---- per-lane softmax over 16 key-scores of query l16 (exp2 domain)
    float vmax = -1e30f;
#pragma unroll
    for (int mt = 0; mt < 4; ++mt)
#pragma unroll
      for (int r = 0; r < 4; ++r) {
        const int key = k0 + mt * 16 + quad * 4 + r;
        st[mt][r] = (key <= q) ? st[mt][r] : -1e9f;   // pre-scaled log2e/8
        vmax = fmaxf(vmax, st[mt][r]);
      }
    vmax = fmaxf(vmax, __shfl_xor(vmax, 16));
    vmax = fmaxf(vmax, __shfl_xor(vmax, 32));
    const float mnew  = fmaxf(m, vmax);
    const float alpha = exp2_hw(m - mnew);
    m = mnew;
    float s = 0.0f;
#pragma unroll
    for (int mt = 0; mt < 4; ++mt)
#pragma unroll
      for (int r = 0; r < 4; ++r) {
        st[mt][r] = exp2_hw(st[mt][r] - mnew);
        s += st[mt][r];
      }
    s += __shfl_xor(s, 16);
    s += __shfl_xor(s, 32);
    l = l * alpha + s;
#pragma unroll
    for (int f = 0; f < 4; ++f)
#pragma unroll
      for (int r = 0; r < 4; ++r) o[f][r] *= alpha;

    // ---- P (row=query l16, cols=keys) -> wave-private LDS, read as B-frags.
    // Single buffer is safe: per-wave DS ops execute in order; lgkmcnt(0)
    // drains writes before reads; next iter's writes follow these reads.
    asm volatile("" ::: "memory");
#pragma unroll
    for (int mt = 0; mt < 4; ++mt) {
      short4 w;
      w.x = f2bf(st[mt][0]); w.y = f2bf(st[mt][1]);
      w.z = f2bf(st[mt][2]); w.w = f2bf(st[mt][3]);
      *(short4*)(P + l16 * 72 + mt * 16 + quad * 4) = w;
    }
    asm volatile("" ::: "memory");
    __builtin_amdgcn_s_waitcnt(0xC07F);   // lgkmcnt(0)
    asm volatile("" ::: "memory");
    const bf16x8 pf0 = *(const bf16x8*)(P + l16 * 72 + quad * 8);
    const bf16x8 pf1 = *(const bf16x8*)(P + l16 * 72 + 32 + quad * 8);
    asm volatile("" ::: "memory");

    // ---- O^T += V^T P^T (A-frags from Vlds, swizzled chunks)
#pragma unroll
    for (int f = 0; f < 4; ++f) {
      const int R = f * 16 + l16;
      const bf16x8 vf0 = *(const bf16x8*)&Vlds[R * 64 + ((quad    ) ^ (R & 7)) * 8];
      const bf16x8 vf1 = *(const bf16x8*)&Vlds[R * 64 + ((quad + 4) ^ (R & 7)) * 8];
      o[f] = __builtin_amdgcn_mfma_f32_16x16x32_bf16(vf0, pf0, o[f], 0, 0, 0);
      o[f] = __builtin_amdgcn_mfma_f32_16x16x32_bf16(vf1, pf1, o[f], 0, 0, 0);
    }
    __syncthreads();   // protect Klds/Vlds before next stage
  }

  // ---- epilogue: O^T C-layout row = dh = f*16+quad*4+r, col = query l16.
  const float inv = 1.0f / l;
#pragma unroll
  for (int f = 0; f < 4; ++f) {
    short4 w;
    w.x = f2bf(o[f][0] * inv);
    w.y = f2bf(o[f][1] * inv);
    w.z = f2bf(o[f][2] * inv);
    w.w = f2bf(o[f][3] * inv);
    *(short4*)(Qp + (size_t)(qw + l16) * DMODEL + f * 16 + quad * 4) = w;
  }
}

// ---------------------------------------------------------------- launch
extern "C" void kernel_launch(void* const* d_in, const int* in_sizes, int n_in,
                              void* d_out, int out_size, void* d_ws, size_t ws_size,
                              hipStream_t stream) {
  const float* x   = (const float*)d_in[0];   // [2,4096,1024]
  const float* Wkv = (const float*)d_in[1];   // [1024,32]
  const float* Wk  = (const float*)d_in[2];   // [32,1024]
  const float* Wv  = (const float*)d_in[3];   // [32,1024]
  const float* Wq  = (const float*)d_in[4];   // [1024,1024]
  const float* Wo  = (const float*)d_in[5];   // [1024,1024]

  char* p = (char*)d_ws;
  auto carve = [&](size_t n) {
    char* r = p;
    p += (n + 255) & ~(size_t)255;
    return r;
  };
  short* xbf  = (short*)carve((size_t)M_ROWS * DMODEL * 2);   // 16 MB
  short* Qb   = (short*)carve((size_t)M_ROWS * DMODEL * 2);   // 16 MB (Q -> AO)
  short* Kb   = (short*)carve((size_t)M_ROWS * DMODEL * 2);   // 16 MB
  short* Vtb  = (short*)carve((size_t)M_ROWS * DMODEL * 2);   // 16 MB
  short* lat  = (short*)carve((size_t)M_ROWS * LATENT * 2);   // 512 KB
  short* WqT  = (short*)carve((size_t)DMODEL * DMODEL * 2);   // 2 MB
  short* WoT  = (short*)carve((size_t)DMODEL * DMODEL * 2);   // 2 MB
  short* WkvT = (short*)carve((size_t)DMODEL * LATENT * 2);   // 64 KB
  short* WkT  = (short*)carve((size_t)LATENT * DMODEL * 2);   // 64 KB
  short* WvT  = (short*)carve((size_t)LATENT * DMODEL * 2);   // 64 KB

  convert_in<<<(M_ROWS * DMODEL / 4 + 255) / 256, 256, 0, stream>>>(x, xbf, M_ROWS * DMODEL);
  convert_transpose<<<(DMODEL * LATENT + 255) / 256, 256, 0, stream>>>(Wkv, WkvT, DMODEL, LATENT, 1.0f);
  convert_transpose<<<(LATENT * DMODEL + 255) / 256, 256, 0, stream>>>(Wk, WkT, LATENT, DMODEL, 1.0f);
  convert_transpose<<<(LATENT * DMODEL + 255) / 256, 256, 0, stream>>>(Wv, WvT, LATENT, DMODEL, 1.0f);
  // Wq scale = (1/sqrt(64)) * log2(e): softmax computed with exp2
  convert_transpose<<<(DMODEL * DMODEL + 255) / 256, 256, 0, stream>>>(Wq, WqT, DMODEL, DMODEL, 0.1803368801111f);
  convert_transpose<<<(DMODEL * DMODEL + 255) / 256, 256, 0, stream>>>(Wo, WoT, DMODEL, DMODEL, 1.0f);

  auto gemm = [&](const short* A, const short* Bt, short* Cs, float* Cf,
                  int M, int K, int N, int mode) {
    int Nw = (N + 63) >> 6;
    int waves = (M / 16) * Nw;
    int blocks = (waves + 3) / 4;
    gemm_bt_kernel<<<blocks, 256, 0, stream>>>(A, Bt, Cs, Cf, M, K, N, mode);
  };

  gemm(xbf, WkvT, lat, nullptr, M_ROWS, DMODEL, LATENT, 0);   // lat = x @ W_kv
  gemm(lat, WkT,  Kb,  nullptr, M_ROWS, LATENT, DMODEL, 0);   // K  [M,1024]
  gemm(lat, WvT,  Vtb, nullptr, M_ROWS, LATENT, DMODEL, 2);   // V^T [B,H,dh,T]
  gemm(xbf, WqT,  Qb,  nullptr, M_ROWS, DMODEL, DMODEL, 0);   // Q (pre-scaled)

  attn_kernel<<<2048, 256, 0, stream>>>(Qb, Kb, Vtb);

  gemm(Qb, WoT, nullptr, (float*)d_out, M_ROWS, DMODEL, DMODEL, 3);  // out fp32
}